// Round 7
// baseline (724.359 us; speedup 1.0000x reference)
//
#include <hip/hip_runtime.h>

#define KC 24
#define DC 128
#define TPB 256
#define NROWS 524288
#define CBS 132            // LDS row stride (16B aligned)
#define NSLICE 8
#define SLICE_STRIDE 3104  // KC*DC + KC + 1 = 3097, padded
#define LOSS_SLOT (KC * DC + KC)
#define ACC_TOTAL (NSLICE * SLICE_STRIDE)

__global__ void vq_zero_acc(float* __restrict__ acc) {
    int i = blockIdx.x * blockDim.x + threadIdx.x;
    if (i < ACC_TOTAL) acc[i] = 0.0f;
}

// ---- Kernel 1: dists/argmin/softmax/weights/idx/soft/hard/loss ----
// LDS = codebook only; z read once; no end barrier.
__global__ __launch_bounds__(TPB, 6) void vq_main(
    const float* __restrict__ z_e, const float* __restrict__ cb,
    float* __restrict__ o_soft, float* __restrict__ o_hard,
    float* __restrict__ o_idx, float* __restrict__ o_w,
    float* __restrict__ acc)
{
    __shared__ float cb_s[KC][CBS];
    __shared__ float wn_s[KC];

    const int tid = threadIdx.x;

    #pragma unroll 1
    for (int i = tid; i < KC * DC; i += TPB)
        cb_s[i >> 7][i & (DC - 1)] = cb[i];
    __syncthreads();
    if (tid < KC) {
        float s = 0.0f;
        #pragma unroll 1
        for (int d = 0; d < DC; ++d) s = fmaf(cb_s[tid][d], cb_s[tid][d], s);
        wn_s[tid] = s;
    }
    __syncthreads();

    const int row = blockIdx.x * TPB + tid;
    const float* zp = z_e + (size_t)row * DC;

    float dv[KC];
    #pragma unroll
    for (int k = 0; k < KC; ++k) dv[k] = 0.0f;
    float zn = 0.0f;

    // ---- single z pass: 4 chunks of 32 floats ----
    #pragma unroll 1
    for (int c = 0; c < 4; ++c) {
        float4 a[8];
        #pragma unroll
        for (int i = 0; i < 8; ++i)
            a[i] = *(const float4*)(zp + c * 32 + 4 * i);
        #pragma unroll
        for (int i = 0; i < 8; ++i)
            zn = fmaf(a[i].x, a[i].x, fmaf(a[i].y, a[i].y,
                 fmaf(a[i].z, a[i].z, fmaf(a[i].w, a[i].w, zn))));
        #pragma unroll
        for (int k = 0; k < KC; ++k) {
            float s = dv[k];
            #pragma unroll
            for (int i = 0; i < 8; ++i) {
                const float4 wv = *(const float4*)(&cb_s[k][c * 32 + 4 * i]);
                s = fmaf(a[i].x, wv.x, fmaf(a[i].y, wv.y,
                    fmaf(a[i].z, wv.z, fmaf(a[i].w, wv.w, s))));
            }
            dv[k] = s;
        }
    }

    // ---- dists, argmin (first-min), softmax ----
    int idx = 0;
    float best = 3.4e38f;
    #pragma unroll
    for (int k = 0; k < KC; ++k) {
        float d = (zn - 2.0f * dv[k]) + wn_s[k];
        dv[k] = d;
        if (d < best) { best = d; idx = k; }
    }
    float ssum = 0.0f;
    #pragma unroll
    for (int k = 0; k < KC; ++k) {
        float e = __expf(best - dv[k]);
        dv[k] = e;
        ssum += e;
    }
    const float inv = 1.0f / ssum;
    #pragma unroll
    for (int k = 0; k < KC; ++k) dv[k] *= inv;   // weights

    #pragma unroll
    for (int q = 0; q < 6; ++q)
        *(float4*)(o_w + (size_t)row * KC + 4 * q) =
            make_float4(dv[4*q], dv[4*q+1], dv[4*q+2], dv[4*q+3]);
    o_idx[row] = (float)idx;

    // loss: min-dist identity; per-wave reduce -> sliced global atomic
    {
        float loss_acc = best;
        #pragma unroll
        for (int off = 32; off > 0; off >>= 1)
            loss_acc += __shfl_down(loss_acc, off);
        if ((tid & 63) == 0)
            atomicAdd(acc + (size_t)(blockIdx.x & (NSLICE - 1)) * SLICE_STRIDE
                      + LOSS_SLOT, loss_acc);
    }

    // ---- soft + hard stores (no z needed) ----
    #pragma unroll 1
    for (int c = 0; c < 4; ++c) {
        float q[32];
        #pragma unroll
        for (int j = 0; j < 32; ++j) q[j] = 0.0f;
        #pragma unroll
        for (int k = 0; k < KC; ++k) {
            const float wk = dv[k];
            #pragma unroll
            for (int i = 0; i < 8; ++i) {
                const float4 wv = *(const float4*)(&cb_s[k][c * 32 + 4 * i]);
                q[4*i+0] = fmaf(wk, wv.x, q[4*i+0]);
                q[4*i+1] = fmaf(wk, wv.y, q[4*i+1]);
                q[4*i+2] = fmaf(wk, wv.z, q[4*i+2]);
                q[4*i+3] = fmaf(wk, wv.w, q[4*i+3]);
            }
        }
        #pragma unroll
        for (int i = 0; i < 8; ++i)
            *(float4*)(o_soft + (size_t)row * DC + c * 32 + 4 * i) =
                make_float4(q[4*i], q[4*i+1], q[4*i+2], q[4*i+3]);
        #pragma unroll
        for (int i = 0; i < 8; ++i) {
            const float4 h = *(const float4*)(&cb_s[idx][c * 32 + 4 * i]);
            *(float4*)(o_hard + (size_t)row * DC + c * 32 + 4 * i) = h;
        }
    }
}

// ---- Kernel 2: ebin + cnt via fully-coalesced cooperative z reads ----
__global__ __launch_bounds__(TPB, 6) void vq_ebin(
    const float* __restrict__ z_e, const float* __restrict__ o_idx,
    float* __restrict__ acc)
{
    __shared__ float ebin[KC][CBS];
    __shared__ float cnt_s[KC];

    const int tid = threadIdx.x;
    const int w   = tid >> 6;
    const int l   = tid & 63;
    const int rg  = l >> 3;
    const int sub = l & 7;
    const int sb4 = sub * 4;

    #pragma unroll 1
    for (int i = tid; i < KC * CBS; i += TPB) (&ebin[0][0])[i] = 0.0f;
    if (tid < KC) cnt_s[tid] = 0.0f;
    __syncthreads();

    const int rbase = (blockIdx.x * 4 + w) * 64;
    const float* gz = z_e + (size_t)rbase * DC;

    int ids[8];
    #pragma unroll
    for (int jj = 0; jj < 8; ++jj)
        ids[jj] = (int)o_idx[rbase + 8 * jj + rg];

    #pragma unroll 1
    for (int c = 0; c < 4; ++c) {
        float4 zc[8];
        #pragma unroll
        for (int jj = 0; jj < 8; ++jj)
            zc[jj] = *(const float4*)(gz + (size_t)(8 * jj + rg) * DC
                                      + c * 32 + sb4);
        #pragma unroll
        for (int jj = 0; jj < 8; ++jj) {
            const int d = c * 32 + sb4;
            atomicAdd(&ebin[ids[jj]][d + 0], zc[jj].x);
            atomicAdd(&ebin[ids[jj]][d + 1], zc[jj].y);
            atomicAdd(&ebin[ids[jj]][d + 2], zc[jj].z);
            atomicAdd(&ebin[ids[jj]][d + 3], zc[jj].w);
        }
    }
    if (sub == 0) {
        #pragma unroll
        for (int jj = 0; jj < 8; ++jj) atomicAdd(&cnt_s[ids[jj]], 1.0f);
    }
    __syncthreads();

    float* accs = acc + (size_t)(blockIdx.x & (NSLICE - 1)) * SLICE_STRIDE;
    #pragma unroll 1
    for (int i = tid; i < KC * DC; i += TPB)
        atomicAdd(&accs[i], ebin[i >> 7][i & (DC - 1)]);
    if (tid < KC) atomicAdd(&accs[KC * DC + tid], cnt_s[tid]);
}

__global__ void vq_epilogue(
    const float* __restrict__ z_e, const float* __restrict__ ema_cs,
    const float* __restrict__ ema_es, const int* __restrict__ rand_idx,
    const float* __restrict__ acc,
    float* __restrict__ o_loss, float* __restrict__ o_cbn,
    float* __restrict__ o_ecs, float* __restrict__ o_ees)
{
    __shared__ float ecs_s[KC], sm_s[KC];
    __shared__ float n_sh;
    const int tid = threadIdx.x;
    if (tid < KC) {
        float csum = 0.0f;
        #pragma unroll
        for (int s = 0; s < NSLICE; ++s)
            csum += acc[s * SLICE_STRIDE + KC * DC + tid];
        ecs_s[tid] = 0.95f * ema_cs[tid] + 0.05f * csum;
    }
    __syncthreads();
    if (tid == 0) {
        float n = 0.0f;
        for (int k = 0; k < KC; ++k) n += ecs_s[k];
        n_sh = n;
    }
    __syncthreads();
    if (tid < KC) {
        float n = n_sh;
        sm_s[tid] = (ecs_s[tid] + 1e-5f) / (n + (float)KC * 1e-5f) * n;
    }
    __syncthreads();
    #pragma unroll 1
    for (int i = tid; i < KC * DC; i += TPB) {
        int k = i >> 7, d = i & (DC - 1);
        float esum = 0.0f;
        #pragma unroll
        for (int s = 0; s < NSLICE; ++s) esum += acc[s * SLICE_STRIDE + i];
        float ees = 0.95f * ema_es[i] + 0.05f * esum;
        float cbn = ees / sm_s[k];
        bool dead = ecs_s[k] < 0.1f;
        float rst = z_e[(size_t)rand_idx[k] * DC + d];
        o_cbn[i] = dead ? rst : cbn;
        o_ees[i] = dead ? rst : ees;
    }
    if (tid < KC) o_ecs[tid] = (ecs_s[tid] < 0.1f) ? 1.0f : ecs_s[tid];
    if (tid == 0) {
        float lsum = 0.0f;
        #pragma unroll
        for (int s = 0; s < NSLICE; ++s)
            lsum += acc[s * SLICE_STRIDE + LOSS_SLOT];
        o_loss[0] = 1.5f * (lsum * (1.0f / 67108864.0f));
    }
}

extern "C" void kernel_launch(void* const* d_in, const int* in_sizes, int n_in,
                              void* d_out, int out_size, void* d_ws, size_t ws_size,
                              hipStream_t stream) {
    const float* z_e    = (const float*)d_in[0];
    const float* cb     = (const float*)d_in[1];
    const float* ema_cs = (const float*)d_in[2];
    const float* ema_es = (const float*)d_in[3];
    const int*   ridx   = (const int*)d_in[4];

    float* out = (float*)d_out;
    float* o_soft = out;                                  // 67108864
    float* o_hard = out + 67108864ll;                     // 67108864
    float* o_idx  = out + 134217728ll;                    // 524288
    float* o_w    = out + 134742016ll;                    // 12582912
    float* o_loss = out + 147324928ll;                    // 1
    float* o_cbn  = out + 147324929ll;                    // 3072
    float* o_ecs  = out + 147328001ll;                    // 24
    float* o_ees  = out + 147328025ll;                    // 3072

    float* acc = (float*)d_ws;

    vq_zero_acc<<<(ACC_TOTAL + TPB - 1) / TPB, TPB, 0, stream>>>(acc);
    vq_main<<<NROWS / TPB, TPB, 0, stream>>>(
        z_e, cb, o_soft, o_hard, o_idx, o_w, acc);
    vq_ebin<<<NROWS / 256, TPB, 0, stream>>>(z_e, o_idx, acc);
    vq_epilogue<<<1, TPB, 0, stream>>>(
        z_e, ema_cs, ema_es, ridx, acc, o_loss, o_cbn, o_ecs, o_ees);
}

// Round 8
// 674.905 us; speedup vs baseline: 1.0733x; 1.0733x over previous
//
#include <hip/hip_runtime.h>

#define KC 24
#define DC 128
#define TPB 256
#define NROWS 524288
#define CBS 132            // cb_s row stride in main (16B aligned)
#define EBS 129            // ebin row stride in ebin kernel (bank spread)
#define NSLICE 8

#define NB_EBIN 512
#define ROWS_PER_EBIN (NROWS / NB_EBIN)   // 1024
#define PSTR 3104                          // partial stride (KC*DC+KC+1=3097 padded)
#define FINAL_OFF (NB_EBIN * PSTR)
#define LOSS_OFF (FINAL_OFF + PSTR)

__global__ void vq_zero_loss(float* __restrict__ acc) {
    if (threadIdx.x < NSLICE) acc[LOSS_OFF + threadIdx.x] = 0.0f;
}

// ---- Kernel 1: dists/argmin/softmax/weights/idx/soft/hard/loss ----
__global__ __launch_bounds__(TPB, 4) void vq_main(
    const float* __restrict__ z_e, const float* __restrict__ cb,
    float* __restrict__ o_soft, float* __restrict__ o_hard,
    float* __restrict__ o_idx, float* __restrict__ o_w,
    float* __restrict__ acc)
{
    __shared__ float cb_s[KC][CBS];
    __shared__ float wn_s[KC];

    const int tid = threadIdx.x;

    #pragma unroll 1
    for (int i = tid; i < KC * DC; i += TPB)
        cb_s[i >> 7][i & (DC - 1)] = cb[i];
    __syncthreads();
    if (tid < KC) {
        float s = 0.0f;
        #pragma unroll 1
        for (int d = 0; d < DC; ++d) s = fmaf(cb_s[tid][d], cb_s[tid][d], s);
        wn_s[tid] = s;
    }
    __syncthreads();

    const int row = blockIdx.x * TPB + tid;
    const float* zp = z_e + (size_t)row * DC;

    float dv[KC];
    #pragma unroll
    for (int k = 0; k < KC; ++k) dv[k] = 0.0f;
    float zn = 0.0f;

    #pragma unroll 1
    for (int c = 0; c < 4; ++c) {
        float4 a[8];
        #pragma unroll
        for (int i = 0; i < 8; ++i)
            a[i] = *(const float4*)(zp + c * 32 + 4 * i);
        #pragma unroll
        for (int i = 0; i < 8; ++i)
            zn = fmaf(a[i].x, a[i].x, fmaf(a[i].y, a[i].y,
                 fmaf(a[i].z, a[i].z, fmaf(a[i].w, a[i].w, zn))));
        #pragma unroll
        for (int k = 0; k < KC; ++k) {
            float s = dv[k];
            #pragma unroll
            for (int i = 0; i < 8; ++i) {
                const float4 wv = *(const float4*)(&cb_s[k][c * 32 + 4 * i]);
                s = fmaf(a[i].x, wv.x, fmaf(a[i].y, wv.y,
                    fmaf(a[i].z, wv.z, fmaf(a[i].w, wv.w, s))));
            }
            dv[k] = s;
        }
    }

    int idx = 0;
    float best = 3.4e38f;
    #pragma unroll
    for (int k = 0; k < KC; ++k) {
        float d = (zn - 2.0f * dv[k]) + wn_s[k];
        dv[k] = d;
        if (d < best) { best = d; idx = k; }
    }
    float ssum = 0.0f;
    #pragma unroll
    for (int k = 0; k < KC; ++k) {
        float e = __expf(best - dv[k]);
        dv[k] = e;
        ssum += e;
    }
    const float inv = 1.0f / ssum;
    #pragma unroll
    for (int k = 0; k < KC; ++k) dv[k] *= inv;   // weights

    #pragma unroll
    for (int q = 0; q < 6; ++q)
        *(float4*)(o_w + (size_t)row * KC + 4 * q) =
            make_float4(dv[4*q], dv[4*q+1], dv[4*q+2], dv[4*q+3]);
    o_idx[row] = (float)idx;

    {
        float loss_acc = best;   // min-dist identity
        #pragma unroll
        for (int off = 32; off > 0; off >>= 1)
            loss_acc += __shfl_down(loss_acc, off);
        if ((tid & 63) == 0)
            atomicAdd(acc + LOSS_OFF + (blockIdx.x & (NSLICE - 1)), loss_acc);
    }

    #pragma unroll 1
    for (int c = 0; c < 4; ++c) {
        float q[32];
        #pragma unroll
        for (int j = 0; j < 32; ++j) q[j] = 0.0f;
        #pragma unroll
        for (int k = 0; k < KC; ++k) {
            const float wk = dv[k];
            #pragma unroll
            for (int i = 0; i < 8; ++i) {
                const float4 wv = *(const float4*)(&cb_s[k][c * 32 + 4 * i]);
                q[4*i+0] = fmaf(wk, wv.x, q[4*i+0]);
                q[4*i+1] = fmaf(wk, wv.y, q[4*i+1]);
                q[4*i+2] = fmaf(wk, wv.z, q[4*i+2]);
                q[4*i+3] = fmaf(wk, wv.w, q[4*i+3]);
            }
        }
        #pragma unroll
        for (int i = 0; i < 8; ++i)
            *(float4*)(o_soft + (size_t)row * DC + c * 32 + 4 * i) =
                make_float4(q[4*i], q[4*i+1], q[4*i+2], q[4*i+3]);
        #pragma unroll
        for (int i = 0; i < 8; ++i) {
            const float4 h = *(const float4*)(&cb_s[idx][c * 32 + 4 * i]);
            *(float4*)(o_hard + (size_t)row * DC + c * 32 + 4 * i) = h;
        }
    }
}

// ---- Kernel 2: ebin + cnt; coalesced reads; NON-ATOMIC partial output ----
__global__ __launch_bounds__(TPB, 4) void vq_ebin(
    const float* __restrict__ z_e, const float* __restrict__ o_idx,
    float* __restrict__ acc)
{
    __shared__ float ebin[KC][EBS];
    __shared__ float cnt_s[KC];

    const int tid = threadIdx.x;
    const int w   = tid >> 6;
    const int l   = tid & 63;
    const int rg  = l >> 3;
    const int sub = l & 7;
    const int sb4 = sub * 4;

    #pragma unroll 1
    for (int i = tid; i < KC * EBS; i += TPB) (&ebin[0][0])[i] = 0.0f;
    if (tid < KC) cnt_s[tid] = 0.0f;
    __syncthreads();

    // block handles ROWS_PER_EBIN rows; wave w: 4 halves of 64 rows
    #pragma unroll 1
    for (int h = 0; h < 4; ++h) {
        const int rbase = blockIdx.x * ROWS_PER_EBIN + w * 256 + h * 64;
        const float* gz = z_e + (size_t)rbase * DC;

        int ids[8];
        #pragma unroll
        for (int jj = 0; jj < 8; ++jj)
            ids[jj] = (int)o_idx[rbase + 8 * jj + rg];

        #pragma unroll 1
        for (int c = 0; c < 4; ++c) {
            float4 zc[8];
            #pragma unroll
            for (int jj = 0; jj < 8; ++jj)
                zc[jj] = *(const float4*)(gz + (size_t)(8 * jj + rg) * DC
                                          + c * 32 + sb4);
            #pragma unroll
            for (int jj = 0; jj < 8; ++jj) {
                const int d = c * 32 + sb4;
                atomicAdd(&ebin[ids[jj]][d + 0], zc[jj].x);
                atomicAdd(&ebin[ids[jj]][d + 1], zc[jj].y);
                atomicAdd(&ebin[ids[jj]][d + 2], zc[jj].z);
                atomicAdd(&ebin[ids[jj]][d + 3], zc[jj].w);
            }
        }
        if (sub == 0) {
            #pragma unroll
            for (int jj = 0; jj < 8; ++jj) atomicAdd(&cnt_s[ids[jj]], 1.0f);
        }
    }
    __syncthreads();

    // non-atomic coalesced partial store
    float* part = acc + (size_t)blockIdx.x * PSTR;
    #pragma unroll 1
    for (int i = tid; i < KC * DC; i += TPB)
        part[i] = ebin[i >> 7][i & (DC - 1)];
    if (tid < KC) part[KC * DC + tid] = cnt_s[tid];
}

// ---- Kernel 3: reduce partials ----
__global__ void vq_reduce(float* __restrict__ acc) {
    const int i = blockIdx.x * blockDim.x + threadIdx.x;
    if (i >= KC * DC + KC) return;
    float s = 0.0f;
    #pragma unroll 4
    for (int b = 0; b < NB_EBIN; ++b)
        s += acc[(size_t)b * PSTR + i];
    acc[FINAL_OFF + i] = s;
}

__global__ void vq_epilogue(
    const float* __restrict__ z_e, const float* __restrict__ ema_cs,
    const float* __restrict__ ema_es, const int* __restrict__ rand_idx,
    const float* __restrict__ acc,
    float* __restrict__ o_loss, float* __restrict__ o_cbn,
    float* __restrict__ o_ecs, float* __restrict__ o_ees)
{
    __shared__ float ecs_s[KC], sm_s[KC];
    __shared__ float n_sh;
    const int tid = threadIdx.x;
    const float* fin = acc + FINAL_OFF;
    if (tid < KC)
        ecs_s[tid] = 0.95f * ema_cs[tid] + 0.05f * fin[KC * DC + tid];
    __syncthreads();
    if (tid == 0) {
        float n = 0.0f;
        for (int k = 0; k < KC; ++k) n += ecs_s[k];
        n_sh = n;
    }
    __syncthreads();
    if (tid < KC) {
        float n = n_sh;
        sm_s[tid] = (ecs_s[tid] + 1e-5f) / (n + (float)KC * 1e-5f) * n;
    }
    __syncthreads();
    #pragma unroll 1
    for (int i = tid; i < KC * DC; i += TPB) {
        int k = i >> 7, d = i & (DC - 1);
        float ees = 0.95f * ema_es[i] + 0.05f * fin[i];
        float cbn = ees / sm_s[k];
        bool dead = ecs_s[k] < 0.1f;
        float rst = z_e[(size_t)rand_idx[k] * DC + d];
        o_cbn[i] = dead ? rst : cbn;
        o_ees[i] = dead ? rst : ees;
    }
    if (tid < KC) o_ecs[tid] = (ecs_s[tid] < 0.1f) ? 1.0f : ecs_s[tid];
    if (tid == 0) {
        float lsum = 0.0f;
        #pragma unroll
        for (int s = 0; s < NSLICE; ++s) lsum += acc[LOSS_OFF + s];
        o_loss[0] = 1.5f * (lsum * (1.0f / 67108864.0f));
    }
}

extern "C" void kernel_launch(void* const* d_in, const int* in_sizes, int n_in,
                              void* d_out, int out_size, void* d_ws, size_t ws_size,
                              hipStream_t stream) {
    const float* z_e    = (const float*)d_in[0];
    const float* cb     = (const float*)d_in[1];
    const float* ema_cs = (const float*)d_in[2];
    const float* ema_es = (const float*)d_in[3];
    const int*   ridx   = (const int*)d_in[4];

    float* out = (float*)d_out;
    float* o_soft = out;                                  // 67108864
    float* o_hard = out + 67108864ll;                     // 67108864
    float* o_idx  = out + 134217728ll;                    // 524288
    float* o_w    = out + 134742016ll;                    // 12582912
    float* o_loss = out + 147324928ll;                    // 1
    float* o_cbn  = out + 147324929ll;                    // 3072
    float* o_ecs  = out + 147328001ll;                    // 24
    float* o_ees  = out + 147328025ll;                    // 3072

    float* acc = (float*)d_ws;

    vq_zero_loss<<<1, 64, 0, stream>>>(acc);
    vq_main<<<NROWS / TPB, TPB, 0, stream>>>(
        z_e, cb, o_soft, o_hard, o_idx, o_w, acc);
    vq_ebin<<<NB_EBIN, TPB, 0, stream>>>(z_e, o_idx, acc);
    vq_reduce<<<(KC * DC + KC + TPB - 1) / TPB, TPB, 0, stream>>>(acc);
    vq_epilogue<<<1, TPB, 0, stream>>>(
        z_e, ema_cs, ema_es, ridx, acc, o_loss, o_cbn, o_ecs, o_ees);
}